// Round 2
// baseline (316.757 us; speedup 1.0000x reference)
//
#include <hip/hip_runtime.h>
#include <stdint.h>

// BinaryConv2D via i8 0/1 MFMA implicit GEMM.
// binarize(v)=+1/-1 (bit/byte = 1 iff v<0).
// out = Kc[hclass][wclass][oc] - 2*Sx9[pixel] + 4*dot01
//   dot01: GEMM over K=9*128 of 0/1 bytes (zero-padded -> pad taps add 0)
//   Sx9  : popcount of in-bounds 3x3 neighborhood bits of x
//   Kc   : sum over valid taps of (128 - 2*Sw_tap[oc])
// Channel order within a tap (both operands): c<64 -> word0 bit c (ch 2c),
// c>=64 -> word1 bit c-64 (ch 2(c-64)+1).
//
// R2: 2 rows/block, 512 thr / 8 waves; wave = 1 Ntile x 4 Mtiles (2 rows x 2).
//     B-fragment reuse 2->4 (halves B L2 traffic), acc stays 64 VGPR,
//     launch_bounds(512,4) -> 2 blocks/CU = 4 waves/SIMD (was 3).

#define IH 56
#define IW 56
#define COUT 256
#define NB 64
#define ROWPX 58
#define PXB 144                 // 128 ch bytes + 16 pad
#define ROWB (ROWPX * PXB)

typedef int v4i  __attribute__((ext_vector_type(4)));
typedef int v16i __attribute__((ext_vector_type(16)));

__device__ __forceinline__ uint32_t nib(uint64_t w, int i) {
    return ((uint32_t)(w >> (4 * i)) & 0xF) * 0x00204081u & 0x01010101u;
}

// ---- pack x: one wave per pixel-quad (4 independent loads -> MLP 4) ----
__global__ void pack_x_kernel(const float* __restrict__ x,
                              uint64_t* __restrict__ xp, int npix) {
    int gtid = blockIdx.x * blockDim.x + threadIdx.x;
    int wave = gtid >> 6, lane = gtid & 63;
    int nw = (gridDim.x * blockDim.x) >> 6;
    const float2* x2 = (const float2*)x;
    int q = npix >> 2;
    for (int p = wave; p < q; p += nw) {
        float2 v0 = x2[(size_t)p * 64 + lane];
        float2 v1 = x2[((size_t)p + q) * 64 + lane];
        float2 v2 = x2[((size_t)p + 2 * q) * 64 + lane];
        float2 v3 = x2[((size_t)p + 3 * q) * 64 + lane];
        uint64_t a0 = __ballot(v0.x < 0.0f), a1 = __ballot(v0.y < 0.0f);
        uint64_t b0 = __ballot(v1.x < 0.0f), b1 = __ballot(v1.y < 0.0f);
        uint64_t c0 = __ballot(v2.x < 0.0f), c1 = __ballot(v2.y < 0.0f);
        uint64_t d0 = __ballot(v3.x < 0.0f), d1 = __ballot(v3.y < 0.0f);
        if (lane == 0) {
            xp[2 * (size_t)p] = a0;             xp[2 * (size_t)p + 1] = a1;
            xp[2 * ((size_t)p + q)] = b0;       xp[2 * ((size_t)p + q) + 1] = b1;
            xp[2 * ((size_t)p + 2 * q)] = c0;   xp[2 * ((size_t)p + 2 * q) + 1] = c1;
            xp[2 * ((size_t)p + 3 * q)] = d0;   xp[2 * ((size_t)p + 3 * q) + 1] = d1;
        }
    }
}

// ---- pack w bits -> wp[(tap*2+hf)*256 + oc], bit l = channel 2l+hf ----
__global__ void pack_w_kernel(const float* __restrict__ w,
                              uint64_t* __restrict__ wp) {
    int gtid = blockIdx.x * blockDim.x + threadIdx.x;
    int wave = gtid >> 6, lane = gtid & 63;
    int nw = (gridDim.x * blockDim.x) >> 6;
    const int ntask = 9 * 2 * COUT;
    for (int t = wave; t < ntask; t += nw) {
        int oc = t & 255, hf = (t >> 8) & 1, tap = t >> 9;
        float v = w[((size_t)(tap * 128 + 2 * lane + hf)) * COUT + oc];
        uint64_t m = __ballot(v < 0.0f);
        if (lane == 0) wp[(size_t)(tap * 2 + hf) * COUT + oc] = m;
    }
}

// ---- swizzle w into MFMA B-fragment order + build Kc table ----
__global__ void swz_w_kernel(const uint64_t* __restrict__ wp,
                             char* __restrict__ bsw, int* __restrict__ kct) {
    int t = blockIdx.x * blockDim.x + threadIdx.x;
    if (t < 36 * 8 * 64) {
        int lane = t & 63, ntks = t >> 6;
        int nt = ntks & 7, ks = ntks >> 3;
        int oc = nt * 32 + (lane & 31);
        int kk = ks * 32 + (lane >> 5) * 16;
        int tap = kk >> 7, c = kk & 127;
        int hf = c >> 6, bit0 = c & 63;
        uint64_t word = wp[(size_t)(tap * 2 + hf) * COUT + oc];
        int4 d;
        d.x = (int)nib(word, (bit0 >> 2) + 0);
        d.y = (int)nib(word, (bit0 >> 2) + 1);
        d.z = (int)nib(word, (bit0 >> 2) + 2);
        d.w = (int)nib(word, (bit0 >> 2) + 3);
        *(int4*)(bsw + (size_t)t * 16) = d;
    } else if (t < 36 * 8 * 64 + 256) {
        int oc = t - 36 * 8 * 64;
        int Sw[9];
#pragma unroll
        for (int tp = 0; tp < 9; ++tp)
            Sw[tp] = __popcll(wp[(size_t)(tp * 2) * COUT + oc]) +
                     __popcll(wp[(size_t)(tp * 2 + 1) * COUT + oc]);
        for (int hc = 0; hc < 3; ++hc)
            for (int wc = 0; wc < 3; ++wc) {
                int K = 0;
                for (int kh = 0; kh < 3; ++kh) {
                    if (hc == 0 && kh == 0) continue;
                    if (hc == 2 && kh == 2) continue;
                    for (int kw = 0; kw < 3; ++kw) {
                        if (wc == 0 && kw == 0) continue;
                        if (wc == 2 && kw == 2) continue;
                        K += 128 - 2 * Sw[kh * 3 + kw];
                    }
                }
                kct[(hc * 3 + wc) * COUT + oc] = K;
            }
    }
}

// ---- conv: block = (n, 2 rows); 8 waves; wave = 4 Mtiles x 1 Ntile ----
// acc = 4x16 = 64 VGPR; B reused across 4 Mtiles -> half the L2 B traffic.
__global__ __launch_bounds__(512, 4) void bconv_mfma(
        const uint64_t* __restrict__ xp,
        const char* __restrict__ bsw,
        const int* __restrict__ kct,
        float* __restrict__ out) {
    __shared__ alignas(16) char xs8[4 * ROWB];   // 33408 B
    __shared__ int pc[4][ROWPX];
    __shared__ int sx9[2][IW];

    int bh = blockIdx.x % 28, n = blockIdx.x / 28;
    int hbase = bh * 2;
    int tid = threadIdx.x;

    // stage + unpack bits -> 0/1 bytes (b128 LDS writes), per-pixel popcounts
    for (int t = tid; t < 4 * ROWPX; t += 512) {
        int row = t / ROWPX, col = t % ROWPX;
        int rr = hbase - 1 + row, cc = col - 1;
        uint64_t w0 = 0, w1 = 0;
        if ((unsigned)rr < IH && (unsigned)cc < IW) {
            const uint64_t* pp = xp + 2 * (((size_t)n * IH + rr) * IW + cc);
            w0 = pp[0]; w1 = pp[1];
        }
        pc[row][col] = __popcll(w0) + __popcll(w1);
        int4* dst4 = (int4*)(xs8 + row * ROWB + col * PXB);
#pragma unroll
        for (int gi = 0; gi < 4; ++gi) {
            int4 d;
            d.x = (int)nib(w0, 4 * gi + 0);
            d.y = (int)nib(w0, 4 * gi + 1);
            d.z = (int)nib(w0, 4 * gi + 2);
            d.w = (int)nib(w0, 4 * gi + 3);
            dst4[gi] = d;
        }
#pragma unroll
        for (int gi = 0; gi < 4; ++gi) {
            int4 d;
            d.x = (int)nib(w1, 4 * gi + 0);
            d.y = (int)nib(w1, 4 * gi + 1);
            d.z = (int)nib(w1, 4 * gi + 2);
            d.w = (int)nib(w1, 4 * gi + 3);
            dst4[4 + gi] = d;
        }
    }
    __syncthreads();

    for (int t = tid; t < 2 * IW; t += 512) {
        int g = t / IW, px = t % IW;
        int s = 0;
#pragma unroll
        for (int kh = 0; kh < 3; ++kh)
            s += pc[g + kh][px] + pc[g + kh][px + 1] + pc[g + kh][px + 2];
        sx9[g][px] = s;
    }
    __syncthreads();

    int wv = tid >> 6, lane = tid & 63;
    int nt = wv;                     // this wave's single N-tile
    int m = lane & 31, half = lane >> 5;

    v16i acc[4];                     // [g*2+mt]
#pragma unroll
    for (int a = 0; a < 4; ++a)
#pragma unroll
        for (int r = 0; r < 16; ++r) acc[a][r] = 0;

    const v4i* bbase = (const v4i*)bsw + (size_t)nt * 64 + lane;
    const char* abase = xs8 + half * 16 + m * PXB;

    // B prefetch: 3 rotating buffers (1 v4i each), distance ~2 MFMA-steps
    v4i b0, b1, b2;

#define LB(buf, ks)                                              \
    do {                                                         \
        buf = bbase[(size_t)(ks) * 512];                         \
    } while (0)

#define STEPK(ks, buf)                                           \
    do {                                                         \
        int _tap = (ks) >> 2, _kc = (ks) & 3;                    \
        const char* _ar = abase + (_tap / 3) * ROWB +            \
                          (_tap % 3) * PXB + _kc * 32;           \
        v4i _a00 = *(const v4i*)(_ar);                           \
        v4i _a01 = *(const v4i*)(_ar + 24 * PXB);                \
        v4i _a10 = *(const v4i*)(_ar + ROWB);                    \
        v4i _a11 = *(const v4i*)(_ar + ROWB + 24 * PXB);         \
        __builtin_amdgcn_s_setprio(1);                           \
        acc[0] = __builtin_amdgcn_mfma_i32_32x32x32_i8(          \
            _a00, buf, acc[0], 0, 0, 0);                         \
        acc[1] = __builtin_amdgcn_mfma_i32_32x32x32_i8(          \
            _a01, buf, acc[1], 0, 0, 0);                         \
        acc[2] = __builtin_amdgcn_mfma_i32_32x32x32_i8(          \
            _a10, buf, acc[2], 0, 0, 0);                         \
        acc[3] = __builtin_amdgcn_mfma_i32_32x32x32_i8(          \
            _a11, buf, acc[3], 0, 0, 0);                         \
        __builtin_amdgcn_s_setprio(0);                           \
    } while (0)

    LB(b0, 0);
    LB(b1, 1);
#pragma unroll
    for (int ks = 0; ks < 36; ks += 3) {
        LB(b2, ks + 2);
        STEPK(ks, b0);
        LB(b0, (ks + 3 < 36) ? ks + 3 : 0);
        STEPK(ks + 1, b1);
        LB(b1, (ks + 4 < 36) ? ks + 4 : 0);
        STEPK(ks + 2, b2);
    }

    // epilogue: o = Kc - 2*Sx9 + 4*acc
    int oc = nt * 32 + m;
#pragma unroll
    for (int g = 0; g < 2; ++g) {
        int h = hbase + g;
        int hc = (h == 0) ? 0 : ((h == IH - 1) ? 2 : 1);
        float* orow = out + (((size_t)n * IH + h) * IW) * COUT;
        int Ki  = kct[(hc * 3 + 1) * COUT + oc];
        int K0  = kct[(hc * 3 + 0) * COUT + oc];
        int K55 = kct[(hc * 3 + 2) * COUT + oc];
#pragma unroll
        for (int mt = 0; mt < 2; ++mt) {
            int Mb = mt ? 24 : 0;
#pragma unroll
            for (int r = 0; r < 16; ++r) {
                int pxr = (r & 3) + 8 * (r >> 2) + 4 * half;
                int px = Mb + pxr;
                int K = Ki;
                if (mt == 0 && r == 0 && half == 0) K = K0;    // px==0
                if (mt == 1 && r == 15 && half == 1) K = K55;  // px==55
                float o = (float)(K - 2 * sx9[g][px] + 4 * acc[g * 2 + mt][r]);
                orow[(size_t)px * COUT + oc] = o;
            }
        }
    }
}

extern "C" void kernel_launch(void* const* d_in, const int* in_sizes, int n_in,
                              void* d_out, int out_size, void* d_ws, size_t ws_size,
                              hipStream_t stream) {
    const float* x = (const float*)d_in[0];
    const float* w = (const float*)d_in[1];
    float* out = (float*)d_out;

    uint64_t* wp  = (uint64_t*)d_ws;                             // 36864 B
    int*      kct = (int*)((char*)d_ws + 36864);                 // 9216 B
    char*     bsw = (char*)d_ws + 46080;                         // 294912 B
    uint64_t* xp  = (uint64_t*)((char*)d_ws + 344064);           // 3211264 B

    const int npix = NB * IH * IW;

    pack_x_kernel<<<6272, 256, 0, stream>>>(x, xp, npix);
    pack_w_kernel<<<288, 256, 0, stream>>>(w, wp);
    swz_w_kernel<<<73, 256, 0, stream>>>(wp, bsw, kct);
    bconv_mfma<<<NB * 28, 512, 0, stream>>>(xp, bsw, kct, out);
}

// Round 3
// 310.145 us; speedup vs baseline: 1.0213x; 1.0213x over previous
//
#include <hip/hip_runtime.h>
#include <stdint.h>

// BinaryConv2D via i8 0/1 MFMA implicit GEMM.
// binarize(v)=+1/-1 (bit/byte = 1 iff v<0).
// out = Kc[hclass][wclass][oc] - 2*Sx9[pixel] + 4*dot01
//   dot01: GEMM over K=9*128 of 0/1 bytes (zero-padded -> pad taps add 0)
//   Sx9  : popcount of in-bounds 3x3 neighborhood bits of x
//   Kc   : sum over valid taps of (128 - 2*Sw_tap[oc])
// Channel order within a tap (both operands): c<64 -> word0 bit c (ch 2c),
// c>=64 -> word1 bit c-64 (ch 2(c-64)+1).
//
// R3: R1 structure (1 row/block, 4 waves, wave = 2Mx2N; A-LDS 20us < MFMA
//     30.6us -- verified R2's 4Mx1N flipped that balance and regressed).
//     Change vs R1: launch_bounds(256,4) -> 4 blocks/CU = 4 waves/SIMD
//     (MFMA-loop live set ~110 VGPR fits 128; LDS 25KB*4 = 100KB < 160KB).

#define IH 56
#define IW 56
#define COUT 256
#define NB 64
#define ROWPX 58
#define PXB 144                 // 128 ch bytes + 16 pad
#define ROWB (ROWPX * PXB)

typedef int v4i  __attribute__((ext_vector_type(4)));
typedef int v16i __attribute__((ext_vector_type(16)));

__device__ __forceinline__ uint32_t nib(uint64_t w, int i) {
    return ((uint32_t)(w >> (4 * i)) & 0xF) * 0x00204081u & 0x01010101u;
}

// ---- pack x: one wave per pixel-quad (4 independent loads -> MLP 4) ----
__global__ void pack_x_kernel(const float* __restrict__ x,
                              uint64_t* __restrict__ xp, int npix) {
    int gtid = blockIdx.x * blockDim.x + threadIdx.x;
    int wave = gtid >> 6, lane = gtid & 63;
    int nw = (gridDim.x * blockDim.x) >> 6;
    const float2* x2 = (const float2*)x;
    int q = npix >> 2;
    for (int p = wave; p < q; p += nw) {
        float2 v0 = x2[(size_t)p * 64 + lane];
        float2 v1 = x2[((size_t)p + q) * 64 + lane];
        float2 v2 = x2[((size_t)p + 2 * q) * 64 + lane];
        float2 v3 = x2[((size_t)p + 3 * q) * 64 + lane];
        uint64_t a0 = __ballot(v0.x < 0.0f), a1 = __ballot(v0.y < 0.0f);
        uint64_t b0 = __ballot(v1.x < 0.0f), b1 = __ballot(v1.y < 0.0f);
        uint64_t c0 = __ballot(v2.x < 0.0f), c1 = __ballot(v2.y < 0.0f);
        uint64_t d0 = __ballot(v3.x < 0.0f), d1 = __ballot(v3.y < 0.0f);
        if (lane == 0) {
            xp[2 * (size_t)p] = a0;             xp[2 * (size_t)p + 1] = a1;
            xp[2 * ((size_t)p + q)] = b0;       xp[2 * ((size_t)p + q) + 1] = b1;
            xp[2 * ((size_t)p + 2 * q)] = c0;   xp[2 * ((size_t)p + 2 * q) + 1] = c1;
            xp[2 * ((size_t)p + 3 * q)] = d0;   xp[2 * ((size_t)p + 3 * q) + 1] = d1;
        }
    }
}

// ---- pack w bits -> wp[(tap*2+hf)*256 + oc], bit l = channel 2l+hf ----
__global__ void pack_w_kernel(const float* __restrict__ w,
                              uint64_t* __restrict__ wp) {
    int gtid = blockIdx.x * blockDim.x + threadIdx.x;
    int wave = gtid >> 6, lane = gtid & 63;
    int nw = (gridDim.x * blockDim.x) >> 6;
    const int ntask = 9 * 2 * COUT;
    for (int t = wave; t < ntask; t += nw) {
        int oc = t & 255, hf = (t >> 8) & 1, tap = t >> 9;
        float v = w[((size_t)(tap * 128 + 2 * lane + hf)) * COUT + oc];
        uint64_t m = __ballot(v < 0.0f);
        if (lane == 0) wp[(size_t)(tap * 2 + hf) * COUT + oc] = m;
    }
}

// ---- swizzle w into MFMA B-fragment order + build Kc table ----
__global__ void swz_w_kernel(const uint64_t* __restrict__ wp,
                             char* __restrict__ bsw, int* __restrict__ kct) {
    int t = blockIdx.x * blockDim.x + threadIdx.x;
    if (t < 36 * 8 * 64) {
        int lane = t & 63, ntks = t >> 6;
        int nt = ntks & 7, ks = ntks >> 3;
        int oc = nt * 32 + (lane & 31);
        int kk = ks * 32 + (lane >> 5) * 16;
        int tap = kk >> 7, c = kk & 127;
        int hf = c >> 6, bit0 = c & 63;
        uint64_t word = wp[(size_t)(tap * 2 + hf) * COUT + oc];
        int4 d;
        d.x = (int)nib(word, (bit0 >> 2) + 0);
        d.y = (int)nib(word, (bit0 >> 2) + 1);
        d.z = (int)nib(word, (bit0 >> 2) + 2);
        d.w = (int)nib(word, (bit0 >> 2) + 3);
        *(int4*)(bsw + (size_t)t * 16) = d;
    } else if (t < 36 * 8 * 64 + 256) {
        int oc = t - 36 * 8 * 64;
        int Sw[9];
#pragma unroll
        for (int tp = 0; tp < 9; ++tp)
            Sw[tp] = __popcll(wp[(size_t)(tp * 2) * COUT + oc]) +
                     __popcll(wp[(size_t)(tp * 2 + 1) * COUT + oc]);
        for (int hc = 0; hc < 3; ++hc)
            for (int wc = 0; wc < 3; ++wc) {
                int K = 0;
                for (int kh = 0; kh < 3; ++kh) {
                    if (hc == 0 && kh == 0) continue;
                    if (hc == 2 && kh == 2) continue;
                    for (int kw = 0; kw < 3; ++kw) {
                        if (wc == 0 && kw == 0) continue;
                        if (wc == 2 && kw == 2) continue;
                        K += 128 - 2 * Sw[kh * 3 + kw];
                    }
                }
                kct[(hc * 3 + wc) * COUT + oc] = K;
            }
    }
}

// ---- conv: block = (n, 1 row); 4 waves; wave = 2 Mtiles x 2 Ntiles ----
__global__ __launch_bounds__(256, 4) void bconv_mfma(
        const uint64_t* __restrict__ xp,
        const char* __restrict__ bsw,
        const int* __restrict__ kct,
        float* __restrict__ out) {
    __shared__ alignas(16) char xs8[3 * ROWB];   // 25056 B
    __shared__ int pc[3][ROWPX];
    __shared__ int sx9[IW];

    int h = blockIdx.x % IH, n = blockIdx.x / IH;
    int tid = threadIdx.x;

    // stage + unpack bits -> 0/1 bytes (b128 LDS writes), per-pixel popcounts
    for (int t = tid; t < 3 * ROWPX; t += 256) {
        int row = t / ROWPX, col = t % ROWPX;
        int rr = h - 1 + row, cc = col - 1;
        uint64_t w0 = 0, w1 = 0;
        if ((unsigned)rr < IH && (unsigned)cc < IW) {
            const uint64_t* pp = xp + 2 * (((size_t)n * IH + rr) * IW + cc);
            w0 = pp[0]; w1 = pp[1];
        }
        pc[row][col] = __popcll(w0) + __popcll(w1);
        int4* dst4 = (int4*)(xs8 + row * ROWB + col * PXB);
#pragma unroll
        for (int gi = 0; gi < 4; ++gi) {
            int4 d;
            d.x = (int)nib(w0, 4 * gi + 0);
            d.y = (int)nib(w0, 4 * gi + 1);
            d.z = (int)nib(w0, 4 * gi + 2);
            d.w = (int)nib(w0, 4 * gi + 3);
            dst4[gi] = d;
        }
#pragma unroll
        for (int gi = 0; gi < 4; ++gi) {
            int4 d;
            d.x = (int)nib(w1, 4 * gi + 0);
            d.y = (int)nib(w1, 4 * gi + 1);
            d.z = (int)nib(w1, 4 * gi + 2);
            d.w = (int)nib(w1, 4 * gi + 3);
            dst4[4 + gi] = d;
        }
    }
    __syncthreads();

    for (int t = tid; t < IW; t += 256) {
        int s = 0;
#pragma unroll
        for (int kh = 0; kh < 3; ++kh)
            s += pc[kh][t] + pc[kh][t + 1] + pc[kh][t + 2];
        sx9[t] = s;
    }
    __syncthreads();

    int wv = tid >> 6, lane = tid & 63;
    int nt0 = wv * 2;                // this wave's 2 N-tiles
    int m = lane & 31, half = lane >> 5;

    v16i acc[2][2];
#pragma unroll
    for (int mt = 0; mt < 2; ++mt)
#pragma unroll
        for (int j = 0; j < 2; ++j)
#pragma unroll
            for (int r = 0; r < 16; ++r) acc[mt][j][r] = 0;

    const v4i* bbase = (const v4i*)bsw + (size_t)nt0 * 64 + lane;
    const char* abase = xs8 + half * 16 + m * PXB;

    // B prefetch: 3 rotating buffers, distance ~2 MFMA-steps
    v4i b0[2], b1[2], b2[2];

#define LB(buf, ks)                                              \
    do {                                                         \
        const v4i* _p = bbase + (size_t)(ks) * 512;              \
        buf[0] = _p[0];   buf[1] = _p[64];                       \
    } while (0)

#define STEPK(ks, buf)                                           \
    do {                                                         \
        int _tap = (ks) >> 2, _kc = (ks) & 3;                    \
        const char* _ar = abase + (_tap / 3) * ROWB +            \
                          (_tap % 3) * PXB + _kc * 32;           \
        v4i _a0 = *(const v4i*)(_ar);                            \
        v4i _a1 = *(const v4i*)(_ar + 24 * PXB);                 \
        __builtin_amdgcn_s_setprio(1);                           \
        _Pragma("unroll")                                        \
        for (int _j = 0; _j < 2; ++_j) {                         \
            acc[0][_j] = __builtin_amdgcn_mfma_i32_32x32x32_i8(  \
                _a0, buf[_j], acc[0][_j], 0, 0, 0);              \
            acc[1][_j] = __builtin_amdgcn_mfma_i32_32x32x32_i8(  \
                _a1, buf[_j], acc[1][_j], 0, 0, 0);              \
        }                                                        \
        __builtin_amdgcn_s_setprio(0);                           \
    } while (0)

    LB(b0, 0);
    LB(b1, 1);
    for (int ks = 0; ks < 36; ks += 3) {
        LB(b2, ks + 2);
        STEPK(ks, b0);
        LB(b0, (ks + 3 < 36) ? ks + 3 : 0);
        STEPK(ks + 1, b1);
        LB(b1, (ks + 4 < 36) ? ks + 4 : 0);
        STEPK(ks + 2, b2);
    }

    // epilogue: o = Kc - 2*Sx9 + 4*acc
    int hc = (h == 0) ? 0 : ((h == IH - 1) ? 2 : 1);
    float* orow = out + (((size_t)n * IH + h) * IW) * COUT;

    int sxv[2][16];
#pragma unroll
    for (int r = 0; r < 16; ++r) {
        int pxr = (r & 3) + 8 * (r >> 2) + 4 * half;
        sxv[0][r] = sx9[pxr];
        sxv[1][r] = sx9[24 + pxr];
    }

#pragma unroll
    for (int j = 0; j < 2; ++j) {
        int ocj = (nt0 + j) * 32 + m;
        int Ki  = kct[(hc * 3 + 1) * COUT + ocj];
        int K0  = kct[(hc * 3 + 0) * COUT + ocj];
        int K55 = kct[(hc * 3 + 2) * COUT + ocj];
#pragma unroll
        for (int mt = 0; mt < 2; ++mt) {
            int Mb = mt ? 24 : 0;
#pragma unroll
            for (int r = 0; r < 16; ++r) {
                int pxr = (r & 3) + 8 * (r >> 2) + 4 * half;
                int px = Mb + pxr;
                int K = Ki;
                if (mt == 0 && r == 0 && half == 0) K = K0;    // px==0
                if (mt == 1 && r == 15 && half == 1) K = K55;  // px==55
                float o = (float)(K - 2 * sxv[mt][r] + 4 * acc[mt][j][r]);
                orow[(size_t)px * COUT + ocj] = o;
            }
        }
    }
}

extern "C" void kernel_launch(void* const* d_in, const int* in_sizes, int n_in,
                              void* d_out, int out_size, void* d_ws, size_t ws_size,
                              hipStream_t stream) {
    const float* x = (const float*)d_in[0];
    const float* w = (const float*)d_in[1];
    float* out = (float*)d_out;

    uint64_t* wp  = (uint64_t*)d_ws;                             // 36864 B
    int*      kct = (int*)((char*)d_ws + 36864);                 // 9216 B
    char*     bsw = (char*)d_ws + 46080;                         // 294912 B
    uint64_t* xp  = (uint64_t*)((char*)d_ws + 344064);           // 3211264 B

    const int npix = NB * IH * IW;

    pack_x_kernel<<<6272, 256, 0, stream>>>(x, xp, npix);
    pack_w_kernel<<<288, 256, 0, stream>>>(w, wp);
    swz_w_kernel<<<73, 256, 0, stream>>>(wp, bsw, kct);
    bconv_mfma<<<NB * IH, 256, 0, stream>>>(xp, bsw, kct, out);
}

// Round 4
// 309.064 us; speedup vs baseline: 1.0249x; 1.0035x over previous
//
#include <hip/hip_runtime.h>
#include <stdint.h>

// BinaryConv2D via i8 0/1 MFMA implicit GEMM.
// binarize(v)=+1/-1 (bit/byte = 1 iff v<0).
// out = Kc[hclass][wclass][oc] - 2*Sx9[pixel] + 4*dot01
//   dot01: GEMM over K=9*128 of 0/1 bytes (zero-padded -> pad taps add 0)
//   Sx9  : popcount of in-bounds 3x3 neighborhood bits of x
//   Kc   : sum over valid taps of (128 - 2*Sw_tap[oc])
// Channel order within a tap (both operands): c<64 -> word0 bit c (ch 2c),
// c>=64 -> word1 bit c-64 (ch 2(c-64)+1).
//
// R4: 2 rows/block, 512 thr / 8 waves, each wave = R1's proven 2Mx2N shape
//     (R3 proved this fits 128 VGPR: (256,4) cap showed no spill regression).
//     Halves B L2 traffic (1.03 GB -> 0.52 GB) + halves staging redundancy.
//     pack_w folded into pack_x launch (independent, block-range split).

#define IH 56
#define IW 56
#define COUT 256
#define NB 64
#define ROWPX 58
#define PXB 144                 // 128 ch bytes + 16 pad
#define ROWB (ROWPX * PXB)

typedef int v4i  __attribute__((ext_vector_type(4)));
typedef int v16i __attribute__((ext_vector_type(16)));

__device__ __forceinline__ uint32_t nib(uint64_t w, int i) {
    return ((uint32_t)(w >> (4 * i)) & 0xF) * 0x00204081u & 0x01010101u;
}

// ---- fused pack: blocks [0,288) pack w bits; blocks [288,6560) pack x ----
__global__ void pack_xw_kernel(const float* __restrict__ x,
                               const float* __restrict__ w,
                               uint64_t* __restrict__ xp,
                               uint64_t* __restrict__ wp, int npix) {
    int tid = threadIdx.x;
    if (blockIdx.x < 288) {
        // pack w -> wp[(tap*2+hf)*256 + oc], bit l = channel 2l+hf
        int gtid = blockIdx.x * 256 + tid;
        int wave = gtid >> 6, lane = gtid & 63;
        const int nw = (288 * 256) >> 6;
        const int ntask = 9 * 2 * COUT;
        for (int t = wave; t < ntask; t += nw) {
            int oc = t & 255, hf = (t >> 8) & 1, tap = t >> 9;
            float v = w[((size_t)(tap * 128 + 2 * lane + hf)) * COUT + oc];
            uint64_t m = __ballot(v < 0.0f);
            if (lane == 0) wp[(size_t)(tap * 2 + hf) * COUT + oc] = m;
        }
    } else {
        // pack x: one wave per pixel-quad (4 independent loads -> MLP 4)
        int gtid = (blockIdx.x - 288) * 256 + tid;
        int wave = gtid >> 6, lane = gtid & 63;
        const int nw = (6272 * 256) >> 6;
        const float2* x2 = (const float2*)x;
        int q = npix >> 2;
        for (int p = wave; p < q; p += nw) {
            float2 v0 = x2[(size_t)p * 64 + lane];
            float2 v1 = x2[((size_t)p + q) * 64 + lane];
            float2 v2 = x2[((size_t)p + 2 * q) * 64 + lane];
            float2 v3 = x2[((size_t)p + 3 * q) * 64 + lane];
            uint64_t a0 = __ballot(v0.x < 0.0f), a1 = __ballot(v0.y < 0.0f);
            uint64_t b0 = __ballot(v1.x < 0.0f), b1 = __ballot(v1.y < 0.0f);
            uint64_t c0 = __ballot(v2.x < 0.0f), c1 = __ballot(v2.y < 0.0f);
            uint64_t d0 = __ballot(v3.x < 0.0f), d1 = __ballot(v3.y < 0.0f);
            if (lane == 0) {
                xp[2 * (size_t)p] = a0;             xp[2 * (size_t)p + 1] = a1;
                xp[2 * ((size_t)p + q)] = b0;       xp[2 * ((size_t)p + q) + 1] = b1;
                xp[2 * ((size_t)p + 2 * q)] = c0;   xp[2 * ((size_t)p + 2 * q) + 1] = c1;
                xp[2 * ((size_t)p + 3 * q)] = d0;   xp[2 * ((size_t)p + 3 * q) + 1] = d1;
            }
        }
    }
}

// ---- swizzle w into MFMA B-fragment order + build Kc table ----
__global__ void swz_w_kernel(const uint64_t* __restrict__ wp,
                             char* __restrict__ bsw, int* __restrict__ kct) {
    int t = blockIdx.x * blockDim.x + threadIdx.x;
    if (t < 36 * 8 * 64) {
        int lane = t & 63, ntks = t >> 6;
        int nt = ntks & 7, ks = ntks >> 3;
        int oc = nt * 32 + (lane & 31);
        int kk = ks * 32 + (lane >> 5) * 16;
        int tap = kk >> 7, c = kk & 127;
        int hf = c >> 6, bit0 = c & 63;
        uint64_t word = wp[(size_t)(tap * 2 + hf) * COUT + oc];
        int4 d;
        d.x = (int)nib(word, (bit0 >> 2) + 0);
        d.y = (int)nib(word, (bit0 >> 2) + 1);
        d.z = (int)nib(word, (bit0 >> 2) + 2);
        d.w = (int)nib(word, (bit0 >> 2) + 3);
        *(int4*)(bsw + (size_t)t * 16) = d;
    } else if (t < 36 * 8 * 64 + 256) {
        int oc = t - 36 * 8 * 64;
        int Sw[9];
#pragma unroll
        for (int tp = 0; tp < 9; ++tp)
            Sw[tp] = __popcll(wp[(size_t)(tp * 2) * COUT + oc]) +
                     __popcll(wp[(size_t)(tp * 2 + 1) * COUT + oc]);
        for (int hc = 0; hc < 3; ++hc)
            for (int wc = 0; wc < 3; ++wc) {
                int K = 0;
                for (int kh = 0; kh < 3; ++kh) {
                    if (hc == 0 && kh == 0) continue;
                    if (hc == 2 && kh == 2) continue;
                    for (int kw = 0; kw < 3; ++kw) {
                        if (wc == 0 && kw == 0) continue;
                        if (wc == 2 && kw == 2) continue;
                        K += 128 - 2 * Sw[kh * 3 + kw];
                    }
                }
                kct[(hc * 3 + wc) * COUT + oc] = K;
            }
    }
}

// ---- conv: block = (n, 2 rows); 8 waves; wave = 2 Mtiles x 2 Ntiles ----
// Wave w: output row hbase+(w>>2), N-tiles (w&3)*2..+1. Same per-wave
// register structure as R1/R3 (fits 128 VGPR) -> 2 blocks/CU = 4 w/SIMD.
__global__ __launch_bounds__(512, 4) void bconv_mfma(
        const uint64_t* __restrict__ xp,
        const char* __restrict__ bsw,
        const int* __restrict__ kct,
        float* __restrict__ out) {
    __shared__ alignas(16) char xs8[4 * ROWB];   // 33408 B
    __shared__ int pc[4][ROWPX];
    __shared__ int sx9[2][IW];

    int bh = blockIdx.x % 28, n = blockIdx.x / 28;
    int hbase = bh * 2;
    int tid = threadIdx.x;

    // stage + unpack bits -> 0/1 bytes (b128 LDS writes), per-pixel popcounts
    for (int t = tid; t < 4 * ROWPX; t += 512) {
        int row = t / ROWPX, col = t % ROWPX;
        int rr = hbase - 1 + row, cc = col - 1;
        uint64_t w0 = 0, w1 = 0;
        if ((unsigned)rr < IH && (unsigned)cc < IW) {
            const uint64_t* pp = xp + 2 * (((size_t)n * IH + rr) * IW + cc);
            w0 = pp[0]; w1 = pp[1];
        }
        pc[row][col] = __popcll(w0) + __popcll(w1);
        int4* dst4 = (int4*)(xs8 + row * ROWB + col * PXB);
#pragma unroll
        for (int gi = 0; gi < 4; ++gi) {
            int4 d;
            d.x = (int)nib(w0, 4 * gi + 0);
            d.y = (int)nib(w0, 4 * gi + 1);
            d.z = (int)nib(w0, 4 * gi + 2);
            d.w = (int)nib(w0, 4 * gi + 3);
            dst4[gi] = d;
        }
#pragma unroll
        for (int gi = 0; gi < 4; ++gi) {
            int4 d;
            d.x = (int)nib(w1, 4 * gi + 0);
            d.y = (int)nib(w1, 4 * gi + 1);
            d.z = (int)nib(w1, 4 * gi + 2);
            d.w = (int)nib(w1, 4 * gi + 3);
            dst4[4 + gi] = d;
        }
    }
    __syncthreads();

    for (int t = tid; t < 2 * IW; t += 512) {
        int g = t / IW, px = t % IW;
        int s = 0;
#pragma unroll
        for (int kh = 0; kh < 3; ++kh)
            s += pc[g + kh][px] + pc[g + kh][px + 1] + pc[g + kh][px + 2];
        sx9[g][px] = s;
    }
    __syncthreads();

    int wv = tid >> 6, lane = tid & 63;
    int g = wv >> 2;                 // output row group (0/1)
    int nt0 = (wv & 3) * 2;          // this wave's 2 N-tiles
    int m = lane & 31, half = lane >> 5;

    v16i acc[2][2];
#pragma unroll
    for (int mt = 0; mt < 2; ++mt)
#pragma unroll
        for (int j = 0; j < 2; ++j)
#pragma unroll
            for (int r = 0; r < 16; ++r) acc[mt][j][r] = 0;

    const v4i* bbase = (const v4i*)bsw + (size_t)nt0 * 64 + lane;
    const char* abase = xs8 + g * ROWB + half * 16 + m * PXB;

    // B prefetch: 3 rotating buffers, distance ~2 MFMA-steps
    v4i b0[2], b1[2], b2[2];

#define LB(buf, ks)                                              \
    do {                                                         \
        const v4i* _p = bbase + (size_t)(ks) * 512;              \
        buf[0] = _p[0];   buf[1] = _p[64];                       \
    } while (0)

#define STEPK(ks, buf)                                           \
    do {                                                         \
        int _tap = (ks) >> 2, _kc = (ks) & 3;                    \
        const char* _ar = abase + (_tap / 3) * ROWB +            \
                          (_tap % 3) * PXB + _kc * 32;           \
        v4i _a0 = *(const v4i*)(_ar);                            \
        v4i _a1 = *(const v4i*)(_ar + 24 * PXB);                 \
        __builtin_amdgcn_s_setprio(1);                           \
        _Pragma("unroll")                                        \
        for (int _j = 0; _j < 2; ++_j) {                         \
            acc[0][_j] = __builtin_amdgcn_mfma_i32_32x32x32_i8(  \
                _a0, buf[_j], acc[0][_j], 0, 0, 0);              \
            acc[1][_j] = __builtin_amdgcn_mfma_i32_32x32x32_i8(  \
                _a1, buf[_j], acc[1][_j], 0, 0, 0);              \
        }                                                        \
        __builtin_amdgcn_s_setprio(0);                           \
    } while (0)

    LB(b0, 0);
    LB(b1, 1);
    for (int ks = 0; ks < 36; ks += 3) {
        LB(b2, ks + 2);
        STEPK(ks, b0);
        LB(b0, (ks + 3 < 36) ? ks + 3 : 0);
        STEPK(ks + 1, b1);
        LB(b1, (ks + 4 < 36) ? ks + 4 : 0);
        STEPK(ks + 2, b2);
    }

    // epilogue: o = Kc - 2*Sx9 + 4*acc
    int h = hbase + g;
    int hc = (h == 0) ? 0 : ((h == IH - 1) ? 2 : 1);
    float* orow = out + (((size_t)n * IH + h) * IW) * COUT;

    int sxv[2][16];
#pragma unroll
    for (int r = 0; r < 16; ++r) {
        int pxr = (r & 3) + 8 * (r >> 2) + 4 * half;
        sxv[0][r] = sx9[g][pxr];
        sxv[1][r] = sx9[g][24 + pxr];
    }

#pragma unroll
    for (int j = 0; j < 2; ++j) {
        int ocj = (nt0 + j) * 32 + m;
        int Ki  = kct[(hc * 3 + 1) * COUT + ocj];
        int K0  = kct[(hc * 3 + 0) * COUT + ocj];
        int K55 = kct[(hc * 3 + 2) * COUT + ocj];
#pragma unroll
        for (int mt = 0; mt < 2; ++mt) {
            int Mb = mt ? 24 : 0;
#pragma unroll
            for (int r = 0; r < 16; ++r) {
                int pxr = (r & 3) + 8 * (r >> 2) + 4 * half;
                int px = Mb + pxr;
                int K = Ki;
                if (mt == 0 && r == 0 && half == 0) K = K0;    // px==0
                if (mt == 1 && r == 15 && half == 1) K = K55;  // px==55
                float o = (float)(K - 2 * sxv[mt][r] + 4 * acc[mt][j][r]);
                orow[(size_t)px * COUT + ocj] = o;
            }
        }
    }
}

extern "C" void kernel_launch(void* const* d_in, const int* in_sizes, int n_in,
                              void* d_out, int out_size, void* d_ws, size_t ws_size,
                              hipStream_t stream) {
    const float* x = (const float*)d_in[0];
    const float* w = (const float*)d_in[1];
    float* out = (float*)d_out;

    uint64_t* wp  = (uint64_t*)d_ws;                             // 36864 B
    int*      kct = (int*)((char*)d_ws + 36864);                 // 9216 B
    char*     bsw = (char*)d_ws + 46080;                         // 294912 B
    uint64_t* xp  = (uint64_t*)((char*)d_ws + 344064);           // 3211264 B

    const int npix = NB * IH * IW;

    pack_xw_kernel<<<6560, 256, 0, stream>>>(x, w, xp, wp, npix);
    swz_w_kernel<<<73, 256, 0, stream>>>(wp, bsw, kct);
    bconv_mfma<<<NB * 28, 512, 0, stream>>>(xp, bsw, kct, out);
}